// Round 6
// baseline (86.161 us; speedup 1.0000x reference)
//
#include <hip/hip_runtime.h>
#include <math.h>

static constexpr float kEps = 1e-5f;

// ---------- kernel 1: transpose w1 -> w1t blocked [49][109][28 qc][4 o] ----------
// reader: output ow = qc + 28*o; one float4 per (kk,oh,qc) feeds 4 strided outputs.
__global__ __launch_bounds__(256)
void transpose_w1(const float* __restrict__ w1, float* __restrict__ t1)
{
    const int tid = blockIdx.x * blockDim.x + threadIdx.x;
    const int nt  = gridDim.x * blockDim.x;
    for (int i = tid; i < 49 * 109 * 112; i += nt) {
        const int kk = i / 12208;          // 109*112
        const int rem = i - kk * 12208;
        const int oh = rem / 112, ow = rem - oh * 112;
        const int qc = ow % 28, o = ow / 28;
        const float v = (ow < 109) ? w1[(oh * 109 + ow) * 49 + kk] : 0.f;
        t1[(((size_t)kk * 109 + oh) * 28 + qc) * 4 + o] = v;
    }
}

// ---------- kernel 2: conv1 + side transposes ----------
// L1: 224 -> conv(7,s2) -> relu -> y[128][109][112] + partial LN sums (16 stripes).
// Strided quads: thread (r,qc) computes outputs {qc,qc+28,qc+56,qc+84} of row oh0+r.
// x reads: 8B lane stride (bank-conflict-free). Weights: coalesced float4.
// Grid dim3(16,65): block id % 8 == stripe % 8 -> stripe's weights stay in one XCD L2.
__global__ __launch_bounds__(256)
void conv1(const float* __restrict__ x, const float* __restrict__ wt,
           const float* __restrict__ bias, float* __restrict__ y,
           float* __restrict__ partial,
           const float* __restrict__ w2, const float* __restrict__ w3,
           const float* __restrict__ w4, const float* __restrict__ w5,
           const float* __restrict__ w6,
           const float* __restrict__ g1, const float* __restrict__ be1,
           float* __restrict__ w2t, float* __restrict__ w3t,
           float* __restrict__ w4t, float* __restrict__ w5t,
           float* __restrict__ w6t,
           float4* __restrict__ g1p, float4* __restrict__ be1p)
{
    constexpr int IN = 224, OUT = 109, RPS = 7, NS = 16;
    constexpr int ROWS = (RPS - 1) * 2 + 7;   // 19
    constexpr int RSTR = 228;                 // padded row stride (floats)
    __shared__ __align__(16) float xs0[ROWS * RSTR + 12];
    __shared__ __align__(16) float xs1[ROWS * RSTR + 12];
    __shared__ float red[4][4];

    const int s = blockIdx.x, bp = blockIdx.y, t = threadIdx.x;

    if (bp == 64) {
        // ---- side work: small weight transposes + LN1-pool param packing ----
        const int tid = s * 256 + t;
        const int nt  = 16 * 256;
        for (int i = tid; i < 25 * 50 * 52; i += nt) {          // w2t [25][50][52]
            const int kk = i / (50 * 52), r = i % (50 * 52);
            const int oh = r / 52, ow = r % 52;
            w2t[i] = (ow < 50) ? w2[(oh * 50 + ow) * 25 + kk] : 0.f;
        }
        for (int i = tid; i < 9 * 2304; i += nt) {              // w3t [9][2304]
            const int kk = i / 2304, idx = i % 2304;
            w3t[i] = w3[idx * 9 + kk];
        }
        for (int i = tid; i < 9 * 22 * 24; i += nt) {           // w4t [9][22][24]
            const int kk = i / (22 * 24), r = i % (22 * 24);
            const int oh = r / 24, ow = r % 24;
            w4t[i] = (ow < 22) ? w4[(oh * 22 + ow) * 9 + kk] : 0.f;
        }
        for (int i = tid; i < 9 * 400; i += nt) {               // w5t [9][400]
            const int kk = i / 400, idx = i % 400;
            w5t[i] = w5[idx * 9 + kk];
        }
        for (int i = tid; i < 9 * 64; i += nt) {                // w6t [9][64]
            const int kk = i / 64, idx = i % 64;
            w6t[i] = w6[idx * 9 + kk];
        }
        for (int i = tid; i < 54 * 54; i += nt) {               // pool-window params
            const int ph = i / 54, pw = i - ph * 54;
            const int i00 = (2 * ph) * 109 + 2 * pw, i10 = i00 + 109;
            g1p[i]  = make_float4(g1[i00],  g1[i00 + 1],  g1[i10],  g1[i10 + 1]);
            be1p[i] = make_float4(be1[i00], be1[i00 + 1], be1[i10], be1[i10 + 1]);
        }
        return;
    }

    const int b0 = 2 * bp, b1 = b0 + 1;
    const int oh0 = s * RPS, ih0 = oh0 * 2;
    const int nrows = min(ROWS, IN - ih0);
    {
        const float4* g0 = (const float4*)(x + ((size_t)b0 * IN + ih0) * IN);
        const float4* g1r = (const float4*)(x + ((size_t)b1 * IN + ih0) * IN);
        const int n4 = nrows * 56;
        for (int i = t; i < n4; i += 256) {
            const int row = i / 56, j = i - row * 56;
            *(float4*)(xs0 + row * RSTR + 4 * j) = g0[row * 56 + j];
            *(float4*)(xs1 + row * RSTR + 4 * j) = g1r[row * 56 + j];
        }
    }
    __syncthreads();

    float lsum0 = 0.f, lsq0 = 0.f, lsum1 = 0.f, lsq1 = 0.f;
    if (t < RPS * 28) {
        const int r = t / 28, qc = t - r * 28;
        const int oh = oh0 + r;
        if (oh < OUT) {
            const float4* wv = (const float4*)wt;
            float acc0[4], acc1[4];
            #pragma unroll
            for (int o = 0; o < 4; ++o) {
                const int ow = qc + 28 * o;
                const float bv = (ow < OUT) ? bias[oh * OUT + ow] : 0.f;
                acc0[o] = bv; acc1[o] = bv;
            }
            #pragma unroll
            for (int kh = 0; kh < 7; ++kh) {
                float4 w[7];
                #pragma unroll
                for (int kw = 0; kw < 7; ++kw)
                    w[kw] = wv[(((size_t)(kh * 7 + kw) * OUT) + oh) * 28 + qc];
                const int ro = (2 * r + kh) * RSTR;
                #pragma unroll
                for (int o = 0; o < 4; ++o) {
                    int cb = 2 * qc + 56 * o;
                    if (o == 3) cb = min(cb, 216);   // masked lanes read valid cols
                    const float* p0 = xs0 + ro + cb;
                    const float* p1 = xs1 + ro + cb;
                    float a0[8], a1[8];
                    #pragma unroll
                    for (int i2 = 0; i2 < 4; ++i2) {
                        const float2 v0 = *(const float2*)(p0 + 2 * i2);
                        const float2 v1 = *(const float2*)(p1 + 2 * i2);
                        a0[2 * i2] = v0.x; a0[2 * i2 + 1] = v0.y;
                        a1[2 * i2] = v1.x; a1[2 * i2 + 1] = v1.y;
                    }
                    #pragma unroll
                    for (int kw = 0; kw < 7; ++kw) {
                        const float wvv = (&w[kw].x)[o];
                        acc0[o] = fmaf(a0[kw], wvv, acc0[o]);
                        acc1[o] = fmaf(a1[kw], wvv, acc1[o]);
                    }
                }
            }
            float* yb0 = y + ((size_t)b0 * OUT + oh) * 112;
            float* yb1 = y + ((size_t)b1 * OUT + oh) * 112;
            #pragma unroll
            for (int o = 0; o < 4; ++o) {
                const int ow = qc + 28 * o;
                if (ow < OUT) {
                    const float v0 = fmaxf(acc0[o], 0.f);
                    const float v1 = fmaxf(acc1[o], 0.f);
                    yb0[ow] = v0; yb1[ow] = v1;
                    lsum0 += v0; lsq0 = fmaf(v0, v0, lsq0);
                    lsum1 += v1; lsq1 = fmaf(v1, v1, lsq1);
                }
            }
        }
    }
    #pragma unroll
    for (int off = 32; off > 0; off >>= 1) {
        lsum0 += __shfl_down(lsum0, off, 64);  lsq0 += __shfl_down(lsq0, off, 64);
        lsum1 += __shfl_down(lsum1, off, 64);  lsq1 += __shfl_down(lsq1, off, 64);
    }
    if ((t & 63) == 0) {
        const int w = t >> 6;
        red[w][0] = lsum0; red[w][1] = lsq0; red[w][2] = lsum1; red[w][3] = lsq1;
    }
    __syncthreads();
    if (t == 0) {
        float a = 0, bq = 0, c = 0, d = 0;
        #pragma unroll
        for (int w = 0; w < 4; ++w) { a += red[w][0]; bq += red[w][1]; c += red[w][2]; d += red[w][3]; }
        partial[((size_t)b0 * NS + s) * 2]     = a;
        partial[((size_t)b0 * NS + s) * 2 + 1] = bq;
        partial[((size_t)b1 * NS + s) * 2]     = c;
        partial[((size_t)b1 * NS + s) * 2 + 1] = d;
    }
}

// ---------- block stats for 16 waves: one barrier, all threads get result ----------
__device__ inline float2 bstats(float ls, float lq, float invN, float (*red)[2], int t)
{
    #pragma unroll
    for (int off = 32; off > 0; off >>= 1) {
        ls += __shfl_down(ls, off, 64);
        lq += __shfl_down(lq, off, 64);
    }
    if ((t & 63) == 0) { red[t >> 6][0] = ls; red[t >> 6][1] = lq; }
    __syncthreads();
    float s = 0.f, q = 0.f;
    #pragma unroll
    for (int w = 0; w < 16; ++w) { s += red[w][0]; q += red[w][1]; }
    const float m = s * invN;
    return make_float2(m, rsqrtf(q * invN - m * m + kEps));
}

// ---------- kernel 3: everything after conv1, one 1024-thread block per sample ----------
__global__ __launch_bounds__(1024)
void tail(const float* __restrict__ y1, const float* __restrict__ partial,
          const float4* __restrict__ g1p, const float4* __restrict__ be1p,
          const float* __restrict__ w2t, const float* __restrict__ b2,
          const float* __restrict__ g2, const float* __restrict__ be2,
          const float* __restrict__ w3t, const float* __restrict__ b3,
          const float* __restrict__ g3, const float* __restrict__ be3,
          const float* __restrict__ w4t, const float* __restrict__ b4,
          const float* __restrict__ g4, const float* __restrict__ be4,
          const float* __restrict__ w5t, const float* __restrict__ b5,
          const float* __restrict__ g5, const float* __restrict__ be5,
          const float* __restrict__ w6t, const float* __restrict__ b6,
          const float* __restrict__ g6, const float* __restrict__ be6,
          const float* __restrict__ fcw, const float* __restrict__ fcb,
          float* __restrict__ out)
{
    __shared__ __align__(16) float xs54[54 * 54 + 8];
    __shared__ __align__(16) float y50[50 * 52];
    __shared__ __align__(16) float y48[48 * 48];
    __shared__ __align__(16) float xs24[24 * 24 + 8];
    __shared__ __align__(16) float y22[22 * 24];
    __shared__ __align__(16) float y20[20 * 20];
    __shared__ __align__(16) float xs10[100];
    __shared__ float y8[64], h[64];
    __shared__ float red[16][2];

    const int b = blockIdx.x, t = threadIdx.x;
    const int lane = t & 63;

    // ---- LN1 stats from the 16 stripe partials: per-wave, barrier-free ----
    float s = 0.f, q = 0.f;
    if (lane < 16) {
        const float2 p = *(const float2*)(partial + ((size_t)b * 16 + lane) * 2);
        s = p.x; q = p.y;
    }
    #pragma unroll
    for (int off = 32; off > 0; off >>= 1) {
        s += __shfl_down(s, off, 64);
        q += __shfl_down(q, off, 64);
    }
    s = __shfl(s, 0, 64); q = __shfl(q, 0, 64);
    const float m1 = s / 11881.f;
    const float r1 = rsqrtf(q / 11881.f - m1 * m1 + kEps);

    // ---- LN1 + 2x2 pool -> xs54 ----
    const float* yb = y1 + (size_t)b * 109 * 112;
    #pragma unroll
    for (int it = 0; it < 3; ++it) {
        const int idx = t + it * 1024;
        if (idx < 54 * 54) {
            const int ph = idx / 54, pw = idx - ph * 54;
            const int r0 = 2 * ph, c0 = 2 * pw;
            const float2 u0 = *(const float2*)(yb + r0 * 112 + c0);
            const float2 u1 = *(const float2*)(yb + (r0 + 1) * 112 + c0);
            const float4 g = g1p[idx], be = be1p[idx];
            const float v0 = (u0.x - m1) * r1 * g.x + be.x;
            const float v1 = (u0.y - m1) * r1 * g.y + be.y;
            const float v2 = (u1.x - m1) * r1 * g.z + be.z;
            const float v3 = (u1.y - m1) * r1 * g.w + be.w;
            xs54[ph * 54 + pw] = fmaxf(fmaxf(v0, v1), fmaxf(v2, v3));
        }
    }
    __syncthreads();

    // ---- L2: 54 -> conv5 -> relu -> y50 ----
    float ls = 0.f, lq = 0.f;
    if (t < 650) {
        const int oh = t / 13, qc = t - oh * 13;
        const int ow0 = qc * 4;
        float acc[4];
        #pragma unroll
        for (int o = 0; o < 4; ++o) acc[o] = (ow0 + o < 50) ? b2[oh * 50 + ow0 + o] : 0.f;
        #pragma unroll
        for (int kh = 0; kh < 5; ++kh) {
            const float* xp = xs54 + (oh + kh) * 54 + ow0;
            float a[8];
            #pragma unroll
            for (int i = 0; i < 4; ++i) {
                const float2 v = *(const float2*)(xp + 2 * i);
                a[2 * i] = v.x; a[2 * i + 1] = v.y;
            }
            #pragma unroll
            for (int kw = 0; kw < 5; ++kw) {
                const float4 w4 = *(const float4*)(w2t + ((size_t)(kh * 5 + kw) * 50 + oh) * 52 + ow0);
                acc[0] = fmaf(a[kw    ], w4.x, acc[0]);
                acc[1] = fmaf(a[kw + 1], w4.y, acc[1]);
                acc[2] = fmaf(a[kw + 2], w4.z, acc[2]);
                acc[3] = fmaf(a[kw + 3], w4.w, acc[3]);
            }
        }
        #pragma unroll
        for (int o = 0; o < 4; ++o) {
            const float v = fmaxf(acc[o], 0.f);
            y50[oh * 52 + ow0 + o] = v;
            if (ow0 + o < 50) { ls += v; lq = fmaf(v, v, lq); }
        }
    }
    const float2 s2 = bstats(ls, lq, 1.f / 2500.f, red, t);

    // ---- LN2 in place ----
    #pragma unroll
    for (int it = 0; it < 3; ++it) {
        const int idx = t + it * 1024;
        if (idx < 2500) {
            const int oh = idx / 50, ow = idx - oh * 50;
            const int p = oh * 52 + ow;
            y50[p] = (y50[p] - s2.x) * s2.y * g2[idx] + be2[idx];
        }
    }
    __syncthreads();

    // ---- L3: 50 -> conv3 -> relu -> y48 ----
    ls = 0.f; lq = 0.f;
    if (t < 576) {
        const int oh = t / 12, qc = t - oh * 12;
        const int ow0 = qc * 4;
        float acc[4];
        #pragma unroll
        for (int o = 0; o < 4; ++o) acc[o] = b3[oh * 48 + ow0 + o];
        #pragma unroll
        for (int kh = 0; kh < 3; ++kh) {
            const float* xp = y50 + (oh + kh) * 52 + ow0;
            float a[6];
            #pragma unroll
            for (int i = 0; i < 3; ++i) {
                const float2 v = *(const float2*)(xp + 2 * i);
                a[2 * i] = v.x; a[2 * i + 1] = v.y;
            }
            #pragma unroll
            for (int kw = 0; kw < 3; ++kw) {
                const float4 w4 = *(const float4*)(w3t + (size_t)(kh * 3 + kw) * 2304 + oh * 48 + ow0);
                acc[0] = fmaf(a[kw    ], w4.x, acc[0]);
                acc[1] = fmaf(a[kw + 1], w4.y, acc[1]);
                acc[2] = fmaf(a[kw + 2], w4.z, acc[2]);
                acc[3] = fmaf(a[kw + 3], w4.w, acc[3]);
            }
        }
        float4 st;
        #pragma unroll
        for (int o = 0; o < 4; ++o) {
            const float v = fmaxf(acc[o], 0.f);
            (&st.x)[o] = v; ls += v; lq = fmaf(v, v, lq);
        }
        *(float4*)(y48 + oh * 48 + ow0) = st;
    }
    const float2 s3 = bstats(ls, lq, 1.f / 2304.f, red, t);

    // ---- LN3 + pool -> xs24 ----
    if (t < 576) {
        const int ph = t / 24, pw = t - ph * 24;
        const int r0 = 2 * ph, c0 = 2 * pw;
        const float2 u0 = *(const float2*)(y48 + r0 * 48 + c0);
        const float2 u1 = *(const float2*)(y48 + (r0 + 1) * 48 + c0);
        const int i00 = r0 * 48 + c0, i10 = i00 + 48;
        const float v0 = (u0.x - s3.x) * s3.y * g3[i00]     + be3[i00];
        const float v1 = (u0.y - s3.x) * s3.y * g3[i00 + 1] + be3[i00 + 1];
        const float v2 = (u1.x - s3.x) * s3.y * g3[i10]     + be3[i10];
        const float v3 = (u1.y - s3.x) * s3.y * g3[i10 + 1] + be3[i10 + 1];
        xs24[ph * 24 + pw] = fmaxf(fmaxf(v0, v1), fmaxf(v2, v3));
    }
    __syncthreads();

    // ---- L4: 24 -> conv3 -> relu -> y22 ----
    ls = 0.f; lq = 0.f;
    if (t < 132) {
        const int oh = t / 6, qc = t - oh * 6;
        const int ow0 = qc * 4;
        float acc[4];
        #pragma unroll
        for (int o = 0; o < 4; ++o) acc[o] = (ow0 + o < 22) ? b4[oh * 22 + ow0 + o] : 0.f;
        #pragma unroll
        for (int kh = 0; kh < 3; ++kh) {
            const float* xp = xs24 + (oh + kh) * 24 + ow0;
            float a[6];
            #pragma unroll
            for (int i = 0; i < 3; ++i) {
                const float2 v = *(const float2*)(xp + 2 * i);
                a[2 * i] = v.x; a[2 * i + 1] = v.y;
            }
            #pragma unroll
            for (int kw = 0; kw < 3; ++kw) {
                const float4 w4 = *(const float4*)(w4t + ((size_t)(kh * 3 + kw) * 22 + oh) * 24 + ow0);
                acc[0] = fmaf(a[kw    ], w4.x, acc[0]);
                acc[1] = fmaf(a[kw + 1], w4.y, acc[1]);
                acc[2] = fmaf(a[kw + 2], w4.z, acc[2]);
                acc[3] = fmaf(a[kw + 3], w4.w, acc[3]);
            }
        }
        #pragma unroll
        for (int o = 0; o < 4; ++o) {
            const float v = fmaxf(acc[o], 0.f);
            y22[oh * 24 + ow0 + o] = v;
            if (ow0 + o < 22) { ls += v; lq = fmaf(v, v, lq); }
        }
    }
    const float2 s4 = bstats(ls, lq, 1.f / 484.f, red, t);

    // ---- LN4 in place ----
    if (t < 484) {
        const int oh = t / 22, ow = t - oh * 22;
        const int p = oh * 24 + ow;
        y22[p] = (y22[p] - s4.x) * s4.y * g4[t] + be4[t];
    }
    __syncthreads();

    // ---- L5: 22 -> conv3 -> relu -> y20 ----
    ls = 0.f; lq = 0.f;
    if (t < 100) {
        const int oh = t / 5, qc = t - oh * 5;
        const int ow0 = qc * 4;
        float acc[4];
        #pragma unroll
        for (int o = 0; o < 4; ++o) acc[o] = b5[oh * 20 + ow0 + o];
        #pragma unroll
        for (int kh = 0; kh < 3; ++kh) {
            const float* xp = y22 + (oh + kh) * 24 + ow0;
            float a[6];
            #pragma unroll
            for (int i = 0; i < 3; ++i) {
                const float2 v = *(const float2*)(xp + 2 * i);
                a[2 * i] = v.x; a[2 * i + 1] = v.y;
            }
            #pragma unroll
            for (int kw = 0; kw < 3; ++kw) {
                const float4 w4 = *(const float4*)(w5t + (size_t)(kh * 3 + kw) * 400 + oh * 20 + ow0);
                acc[0] = fmaf(a[kw    ], w4.x, acc[0]);
                acc[1] = fmaf(a[kw + 1], w4.y, acc[1]);
                acc[2] = fmaf(a[kw + 2], w4.z, acc[2]);
                acc[3] = fmaf(a[kw + 3], w4.w, acc[3]);
            }
        }
        #pragma unroll
        for (int o = 0; o < 4; ++o) {
            const float v = fmaxf(acc[o], 0.f);
            y20[oh * 20 + ow0 + o] = v;
            ls += v; lq = fmaf(v, v, lq);
        }
    }
    const float2 s5 = bstats(ls, lq, 1.f / 400.f, red, t);

    // ---- LN5 + pool -> xs10 ----
    if (t < 100) {
        const int ph = t / 10, pw = t - ph * 10;
        const int r0 = 2 * ph, c0 = 2 * pw;
        const float2 u0 = *(const float2*)(y20 + r0 * 20 + c0);
        const float2 u1 = *(const float2*)(y20 + (r0 + 1) * 20 + c0);
        const int i00 = r0 * 20 + c0, i10 = i00 + 20;
        const float v0 = (u0.x - s5.x) * s5.y * g5[i00]     + be5[i00];
        const float v1 = (u0.y - s5.x) * s5.y * g5[i00 + 1] + be5[i00 + 1];
        const float v2 = (u1.x - s5.x) * s5.y * g5[i10]     + be5[i10];
        const float v3 = (u1.y - s5.x) * s5.y * g5[i10 + 1] + be5[i10 + 1];
        xs10[ph * 10 + pw] = fmaxf(fmaxf(v0, v1), fmaxf(v2, v3));
    }
    __syncthreads();

    // ---- L6: 10 -> conv3 -> relu -> y8 ----
    ls = 0.f; lq = 0.f;
    if (t < 16) {
        const int oh = t / 2, qc = t - oh * 2;
        const int ow0 = qc * 4;
        float acc[4];
        #pragma unroll
        for (int o = 0; o < 4; ++o) acc[o] = b6[oh * 8 + ow0 + o];
        #pragma unroll
        for (int kh = 0; kh < 3; ++kh) {
            const float* xp = xs10 + (oh + kh) * 10 + ow0;
            float a[6];
            #pragma unroll
            for (int i = 0; i < 3; ++i) {
                const float2 v = *(const float2*)(xp + 2 * i);
                a[2 * i] = v.x; a[2 * i + 1] = v.y;
            }
            #pragma unroll
            for (int kw = 0; kw < 3; ++kw) {
                const float4 w4 = *(const float4*)(w6t + (size_t)(kh * 3 + kw) * 64 + oh * 8 + ow0);
                acc[0] = fmaf(a[kw    ], w4.x, acc[0]);
                acc[1] = fmaf(a[kw + 1], w4.y, acc[1]);
                acc[2] = fmaf(a[kw + 2], w4.z, acc[2]);
                acc[3] = fmaf(a[kw + 3], w4.w, acc[3]);
            }
        }
        #pragma unroll
        for (int o = 0; o < 4; ++o) {
            const float v = fmaxf(acc[o], 0.f);
            y8[oh * 8 + ow0 + o] = v;
            ls += v; lq = fmaf(v, v, lq);
        }
    }
    const float2 s6 = bstats(ls, lq, 1.f / 64.f, red, t);

    // ---- LN6 -> h ----
    if (t < 64) h[t] = (y8[t] - s6.x) * s6.y * g6[t] + be6[t];
    __syncthreads();

    // ---- FC 64 -> 1000 (1 task/thread) + softmax ----
    float lj = -INFINITY;
    if (t < 1000) {
        const float4* wr = (const float4*)(fcw + (size_t)t * 64);
        float acc = fcb[t];
        #pragma unroll
        for (int k = 0; k < 16; ++k) {
            const float4 w4 = wr[k];
            acc = fmaf(h[4 * k], w4.x,
                  fmaf(h[4 * k + 1], w4.y,
                  fmaf(h[4 * k + 2], w4.z,
                  fmaf(h[4 * k + 3], w4.w, acc))));
        }
        lj = acc;
    }
    float mx = lj;
    #pragma unroll
    for (int off = 32; off > 0; off >>= 1) mx = fmaxf(mx, __shfl_down(mx, off, 64));
    if (lane == 0) red[t >> 6][0] = mx;
    __syncthreads();
    float gmax = red[0][0];
    #pragma unroll
    for (int w = 1; w < 16; ++w) gmax = fmaxf(gmax, red[w][0]);

    const float e = (t < 1000) ? __expf(lj - gmax) : 0.f;
    float ssum = e;
    #pragma unroll
    for (int off = 32; off > 0; off >>= 1) ssum += __shfl_down(ssum, off, 64);
    if (lane == 0) red[t >> 6][1] = ssum;
    __syncthreads();
    float tot = 0.f;
    #pragma unroll
    for (int w = 0; w < 16; ++w) tot += red[w][1];
    if (t < 1000) out[(size_t)b * 1000 + t] = e / tot;
}

extern "C" void kernel_launch(void* const* d_in, const int* in_sizes, int n_in,
                              void* d_out, int out_size, void* d_ws, size_t ws_size,
                              hipStream_t stream) {
    const float* x   = (const float*)d_in[0];
    const float* w1  = (const float*)d_in[1];
    const float* b1  = (const float*)d_in[2];
    const float* g1  = (const float*)d_in[3];
    const float* be1 = (const float*)d_in[4];
    const float* w2  = (const float*)d_in[5];
    const float* b2  = (const float*)d_in[6];
    const float* g2  = (const float*)d_in[7];
    const float* be2 = (const float*)d_in[8];
    const float* w3  = (const float*)d_in[9];
    const float* b3  = (const float*)d_in[10];
    const float* g3  = (const float*)d_in[11];
    const float* be3 = (const float*)d_in[12];
    const float* w4  = (const float*)d_in[13];
    const float* b4  = (const float*)d_in[14];
    const float* g4  = (const float*)d_in[15];
    const float* be4 = (const float*)d_in[16];
    const float* w5  = (const float*)d_in[17];
    const float* b5  = (const float*)d_in[18];
    const float* g5  = (const float*)d_in[19];
    const float* be5 = (const float*)d_in[20];
    const float* w6  = (const float*)d_in[21];
    const float* b6  = (const float*)d_in[22];
    const float* g6  = (const float*)d_in[23];
    const float* be6 = (const float*)d_in[24];
    const float* fcw = (const float*)d_in[25];
    const float* fcb = (const float*)d_in[26];

    float* y1p  = (float*)d_ws;                 // 128*109*112 = 1,562,624
    float* w1t  = y1p  + 1562624;               // 49*109*112  =   598,192
    float* w2t  = w1t  + 598192;                // 25*50*52    =    65,000
    float* w3t  = w2t  + 65000;                 // 9*2304      =    20,736
    float* w4t  = w3t  + 20736;                 // 9*22*24     =     4,752
    float* w5t  = w4t  + 4752;                  // 9*400       =     3,600
    float* w6t  = w5t  + 3600;                  // 9*64        =       576
    float* part = w6t  + 576;                   // 128*16*2    =     4,096
    float* g1pp = part + 4096;                  // 2916*4      =    11,664
    float* be1pp= g1pp + 11664;                 // 2916*4      =    11,664

    transpose_w1<<<512, 256, 0, stream>>>(w1, w1t);

    conv1<<<dim3(16, 65), 256, 0, stream>>>(x, w1t, b1, y1p, part,
                                            w2, w3, w4, w5, w6, g1, be1,
                                            w2t, w3t, w4t, w5t, w6t,
                                            (float4*)g1pp, (float4*)be1pp);

    tail<<<128, 1024, 0, stream>>>(y1p, part,
                                   (const float4*)g1pp, (const float4*)be1pp,
                                   w2t, b2, g2, be2,
                                   w3t, b3, g3, be3,
                                   w4t, b4, g4, be4,
                                   w5t, b5, g5, be5,
                                   w6t, b6, g6, be6,
                                   fcw, fcb, (float*)d_out);
}

// Round 7
// 67.734 us; speedup vs baseline: 1.2720x; 1.2720x over previous
//
#include <hip/hip_runtime.h>
#include <math.h>

static constexpr float kEps = 1e-5f;

// ---------- kernel 1: tiled transpose w1 -> w1t [49][109][112] ----------
// Stage 64 consecutive idx rows (64x49 floats) in LDS, write transposed coalesced.
// Pad cols 109..111 are left as garbage: never read by a valid conv1 output.
__global__ __launch_bounds__(256)
void transpose_w1(const float* __restrict__ w1, float* __restrict__ t1)
{
    __shared__ float ws[64 * 49];
    const int b = blockIdx.x, t = threadIdx.x;
    const int base = b * 64;
    const int n = min(64, 11881 - base);
    for (int i = t; i < n * 49; i += 256) ws[i] = w1[(size_t)base * 49 + i];
    __syncthreads();
    for (int i = t; i < 49 * 64; i += 256) {
        const int kk = i >> 6, l = i & 63;
        if (l < n) {
            const int idx = base + l;
            const int oh = idx / 109, ow = idx - 109 * oh;
            t1[((size_t)kk * 109 + oh) * 112 + ow] = ws[l * 49 + kk];
        }
    }
}

// ---------- kernel 2: conv1 + side transposes ----------
// L1: 224 -> conv(7,s2) -> relu -> y[128][109][112] + partial LN sums (14 stripes).
// Thread (r,qc) computes output pair {2qc, 2qc+1} for 2 samples.
// x staged DEINTERLEAVED (even/odd cols) -> all LDS reads are b64 @ 8B lane stride
// (conflict-free optimum). Weights read as coalesced float2 from [kk][oh][112].
__global__ __launch_bounds__(448)
void conv1(const float* __restrict__ x, const float* __restrict__ wt,
           const float* __restrict__ bias, float* __restrict__ y,
           float* __restrict__ partial,
           const float* __restrict__ w2, const float* __restrict__ w3,
           const float* __restrict__ w4, const float* __restrict__ w5,
           const float* __restrict__ w6,
           const float* __restrict__ g1, const float* __restrict__ be1,
           float* __restrict__ w2t, float* __restrict__ w3t,
           float* __restrict__ w4t, float* __restrict__ w5t,
           float* __restrict__ w6t,
           float4* __restrict__ g1p, float4* __restrict__ be1p)
{
    constexpr int IN = 224, OUT = 109, RPS = 8, NSTR = 14;
    constexpr int ROWS = (RPS - 1) * 2 + 7;   // 21
    constexpr int HW = 114;                   // padded half-row (112 + 2 slack)
    __shared__ __align__(8) float xe[2 * ROWS * HW];
    __shared__ __align__(8) float xo[2 * ROWS * HW];
    __shared__ float red[7][4];

    const int s = blockIdx.x, bp = blockIdx.y, t = threadIdx.x;

    if (bp == 64) {
        // ---- side work: small weight transposes + LN1-pool param packing ----
        const int tid = s * 448 + t;
        const int nt  = 14 * 448;
        for (int i = tid; i < 25 * 50 * 52; i += nt) {          // w2t [25][50][52]
            const int kk = i / (50 * 52), r = i % (50 * 52);
            const int oh = r / 52, ow = r % 52;
            w2t[i] = (ow < 50) ? w2[(oh * 50 + ow) * 25 + kk] : 0.f;
        }
        for (int i = tid; i < 9 * 2304; i += nt) {              // w3t [9][2304]
            const int kk = i / 2304, idx = i % 2304;
            w3t[i] = w3[idx * 9 + kk];
        }
        for (int i = tid; i < 9 * 22 * 24; i += nt) {           // w4t [9][22][24]
            const int kk = i / (22 * 24), r = i % (22 * 24);
            const int oh = r / 24, ow = r % 24;
            w4t[i] = (ow < 22) ? w4[(oh * 22 + ow) * 9 + kk] : 0.f;
        }
        for (int i = tid; i < 9 * 400; i += nt) {               // w5t [9][400]
            const int kk = i / 400, idx = i % 400;
            w5t[i] = w5[idx * 9 + kk];
        }
        for (int i = tid; i < 9 * 64; i += nt) {                // w6t [9][64]
            const int kk = i / 64, idx = i % 64;
            w6t[i] = w6[idx * 9 + kk];
        }
        for (int i = tid; i < 54 * 54; i += nt) {               // pool-window params
            const int ph = i / 54, pw = i - ph * 54;
            const int i00 = (2 * ph) * 109 + 2 * pw, i10 = i00 + 109;
            g1p[i]  = make_float4(g1[i00],  g1[i00 + 1],  g1[i10],  g1[i10 + 1]);
            be1p[i] = make_float4(be1[i00], be1[i00 + 1], be1[i10], be1[i10 + 1]);
        }
        return;
    }

    const int b0 = 2 * bp, b1 = b0 + 1;
    const int oh0 = s * RPS, ih0 = oh0 * 2;
    const int nrows = min(ROWS, IN - ih0);

    // ---- stage x deinterleaved: xe[i]=col 2i, xo[i]=col 2i+1 ----
    {
        const int n4 = nrows * 56;
        for (int i = t; i < 2 * n4; i += 448) {
            const int smp = (i < n4) ? 0 : 1;
            const int rem = i - smp * n4;
            const int row = rem / 56, j = rem - row * 56;
            const int bb = smp ? b1 : b0;
            const float4 v = *(const float4*)(x + ((size_t)bb * IN + ih0 + row) * IN + 4 * j);
            const int o = (smp * ROWS + row) * HW + 2 * j;
            *(float2*)(xe + o) = make_float2(v.x, v.z);
            *(float2*)(xo + o) = make_float2(v.y, v.w);
        }
    }
    __syncthreads();

    float ls0 = 0.f, lq0 = 0.f, ls1 = 0.f, lq1 = 0.f;
    {
        const int r = t / 56, qc = t - r * 56;
        const int oh = oh0 + r;
        if (oh < OUT && qc < 55) {
            const bool valid1 = (2 * qc + 1 < OUT);   // false only at qc==54
            float acc00 = bias[oh * OUT + 2 * qc];
            float acc01 = valid1 ? bias[oh * OUT + 2 * qc + 1] : 0.f;
            float acc10 = acc00, acc11 = acc01;
            #pragma unroll
            for (int kh = 0; kh < 7; ++kh) {
                const int lr = 2 * r + kh;
                const int off0 = lr * HW + 2 * qc;
                const int off1 = (ROWS + lr) * HW + 2 * qc;
                float e0[5], o0[4], e1[5], o1[4];
                { const float2 u = *(const float2*)(xe + off0);     e0[0]=u.x; e0[1]=u.y; }
                { const float2 u = *(const float2*)(xe + off0 + 2); e0[2]=u.x; e0[3]=u.y; }
                e0[4] = xe[off0 + 4];
                { const float2 u = *(const float2*)(xo + off0);     o0[0]=u.x; o0[1]=u.y; }
                { const float2 u = *(const float2*)(xo + off0 + 2); o0[2]=u.x; o0[3]=u.y; }
                { const float2 u = *(const float2*)(xe + off1);     e1[0]=u.x; e1[1]=u.y; }
                { const float2 u = *(const float2*)(xe + off1 + 2); e1[2]=u.x; e1[3]=u.y; }
                e1[4] = xe[off1 + 4];
                { const float2 u = *(const float2*)(xo + off1);     o1[0]=u.x; o1[1]=u.y; }
                { const float2 u = *(const float2*)(xo + off1 + 2); o1[2]=u.x; o1[3]=u.y; }
                #pragma unroll
                for (int kw = 0; kw < 7; ++kw) {
                    const float2 w2v = *(const float2*)(wt + ((size_t)(kh * 7 + kw) * OUT + oh) * 112 + 2 * qc);
                    // out0 at col 4qc+kw ; out1 at col 4qc+2+kw (window index +1)
                    const int hi = kw >> 1;
                    const float xa0 = (kw & 1) ? o0[hi] : e0[hi];
                    const float xb0 = (kw & 1) ? o0[hi + 1] : e0[hi + 1];
                    const float xa1 = (kw & 1) ? o1[hi] : e1[hi];
                    const float xb1 = (kw & 1) ? o1[hi + 1] : e1[hi + 1];
                    acc00 = fmaf(xa0, w2v.x, acc00);
                    acc01 = fmaf(xb0, w2v.y, acc01);
                    acc10 = fmaf(xa1, w2v.x, acc10);
                    acc11 = fmaf(xb1, w2v.y, acc11);
                }
            }
            const float v00 = fmaxf(acc00, 0.f), v01 = fmaxf(acc01, 0.f);
            const float v10 = fmaxf(acc10, 0.f), v11 = fmaxf(acc11, 0.f);
            float* r0 = y + ((size_t)b0 * OUT + oh) * 112 + 2 * qc;
            float* r1 = y + ((size_t)b1 * OUT + oh) * 112 + 2 * qc;
            if (valid1) {
                *(float2*)r0 = make_float2(v00, v01);
                *(float2*)r1 = make_float2(v10, v11);
                ls0 += v00 + v01; lq0 = fmaf(v00, v00, fmaf(v01, v01, lq0));
                ls1 += v10 + v11; lq1 = fmaf(v10, v10, fmaf(v11, v11, lq1));
            } else {
                r0[0] = v00; r1[0] = v10;
                ls0 += v00; lq0 = fmaf(v00, v00, lq0);
                ls1 += v10; lq1 = fmaf(v10, v10, lq1);
            }
        }
    }
    #pragma unroll
    for (int off = 32; off > 0; off >>= 1) {
        ls0 += __shfl_down(ls0, off, 64);  lq0 += __shfl_down(lq0, off, 64);
        ls1 += __shfl_down(ls1, off, 64);  lq1 += __shfl_down(lq1, off, 64);
    }
    if ((t & 63) == 0) {
        const int w = t >> 6;
        red[w][0] = ls0; red[w][1] = lq0; red[w][2] = ls1; red[w][3] = lq1;
    }
    __syncthreads();
    if (t == 0) {
        float a = 0, bq = 0, c = 0, d = 0;
        #pragma unroll
        for (int w = 0; w < 7; ++w) { a += red[w][0]; bq += red[w][1]; c += red[w][2]; d += red[w][3]; }
        partial[((size_t)b0 * NSTR + s) * 2]     = a;
        partial[((size_t)b0 * NSTR + s) * 2 + 1] = bq;
        partial[((size_t)b1 * NSTR + s) * 2]     = c;
        partial[((size_t)b1 * NSTR + s) * 2 + 1] = d;
    }
}

// ---------- block stats for 16 waves: one barrier, all threads get result ----------
__device__ inline float2 bstats(float ls, float lq, float invN, float (*red)[2], int t)
{
    #pragma unroll
    for (int off = 32; off > 0; off >>= 1) {
        ls += __shfl_down(ls, off, 64);
        lq += __shfl_down(lq, off, 64);
    }
    if ((t & 63) == 0) { red[t >> 6][0] = ls; red[t >> 6][1] = lq; }
    __syncthreads();
    float s = 0.f, q = 0.f;
    #pragma unroll
    for (int w = 0; w < 16; ++w) { s += red[w][0]; q += red[w][1]; }
    const float m = s * invN;
    return make_float2(m, rsqrtf(q * invN - m * m + kEps));
}

// ---------- kernel 3: everything after conv1, one 1024-thread block per sample ----------
__global__ __launch_bounds__(1024)
void tail(const float* __restrict__ y1, const float* __restrict__ partial,
          const float4* __restrict__ g1p, const float4* __restrict__ be1p,
          const float* __restrict__ w2t, const float* __restrict__ b2,
          const float* __restrict__ g2, const float* __restrict__ be2,
          const float* __restrict__ w3t, const float* __restrict__ b3,
          const float* __restrict__ g3, const float* __restrict__ be3,
          const float* __restrict__ w4t, const float* __restrict__ b4,
          const float* __restrict__ g4, const float* __restrict__ be4,
          const float* __restrict__ w5t, const float* __restrict__ b5,
          const float* __restrict__ g5, const float* __restrict__ be5,
          const float* __restrict__ w6t, const float* __restrict__ b6,
          const float* __restrict__ g6, const float* __restrict__ be6,
          const float* __restrict__ fcw, const float* __restrict__ fcb,
          float* __restrict__ out)
{
    __shared__ __align__(16) float xs54[54 * 54 + 8];
    __shared__ __align__(16) float y50[50 * 52];
    __shared__ __align__(16) float y48[48 * 48];
    __shared__ __align__(16) float xs24[24 * 24 + 8];
    __shared__ __align__(16) float y22[22 * 24];
    __shared__ __align__(16) float y20[20 * 20];
    __shared__ __align__(16) float xs10[100];
    __shared__ float y8[64], h[64];
    __shared__ float red[16][2];

    const int b = blockIdx.x, t = threadIdx.x;
    const int lane = t & 63;

    // ---- LN1 stats from the 14 stripe partials: per-wave, barrier-free ----
    float s = 0.f, q = 0.f;
    if (lane < 14) {
        const float2 p = *(const float2*)(partial + ((size_t)b * 14 + lane) * 2);
        s = p.x; q = p.y;
    }
    #pragma unroll
    for (int off = 32; off > 0; off >>= 1) {
        s += __shfl_down(s, off, 64);
        q += __shfl_down(q, off, 64);
    }
    s = __shfl(s, 0, 64); q = __shfl(q, 0, 64);
    const float m1 = s / 11881.f;
    const float r1 = rsqrtf(q / 11881.f - m1 * m1 + kEps);

    // ---- LN1 + 2x2 pool -> xs54 ----
    const float* yb = y1 + (size_t)b * 109 * 112;
    #pragma unroll
    for (int it = 0; it < 3; ++it) {
        const int idx = t + it * 1024;
        if (idx < 54 * 54) {
            const int ph = idx / 54, pw = idx - ph * 54;
            const int r0 = 2 * ph, c0 = 2 * pw;
            const float2 u0 = *(const float2*)(yb + r0 * 112 + c0);
            const float2 u1 = *(const float2*)(yb + (r0 + 1) * 112 + c0);
            const float4 g = g1p[idx], be = be1p[idx];
            const float v0 = (u0.x - m1) * r1 * g.x + be.x;
            const float v1 = (u0.y - m1) * r1 * g.y + be.y;
            const float v2 = (u1.x - m1) * r1 * g.z + be.z;
            const float v3 = (u1.y - m1) * r1 * g.w + be.w;
            xs54[ph * 54 + pw] = fmaxf(fmaxf(v0, v1), fmaxf(v2, v3));
        }
    }
    __syncthreads();

    // ---- L2: 54 -> conv5 -> relu -> y50 ----
    float ls = 0.f, lq = 0.f;
    if (t < 650) {
        const int oh = t / 13, qc = t - oh * 13;
        const int ow0 = qc * 4;
        float acc[4];
        #pragma unroll
        for (int o = 0; o < 4; ++o) acc[o] = (ow0 + o < 50) ? b2[oh * 50 + ow0 + o] : 0.f;
        #pragma unroll
        for (int kh = 0; kh < 5; ++kh) {
            const float* xp = xs54 + (oh + kh) * 54 + ow0;
            float a[8];
            #pragma unroll
            for (int i = 0; i < 4; ++i) {
                const float2 v = *(const float2*)(xp + 2 * i);
                a[2 * i] = v.x; a[2 * i + 1] = v.y;
            }
            #pragma unroll
            for (int kw = 0; kw < 5; ++kw) {
                const float4 w4 = *(const float4*)(w2t + ((size_t)(kh * 5 + kw) * 50 + oh) * 52 + ow0);
                acc[0] = fmaf(a[kw    ], w4.x, acc[0]);
                acc[1] = fmaf(a[kw + 1], w4.y, acc[1]);
                acc[2] = fmaf(a[kw + 2], w4.z, acc[2]);
                acc[3] = fmaf(a[kw + 3], w4.w, acc[3]);
            }
        }
        #pragma unroll
        for (int o = 0; o < 4; ++o) {
            const float v = fmaxf(acc[o], 0.f);
            y50[oh * 52 + ow0 + o] = v;
            if (ow0 + o < 50) { ls += v; lq = fmaf(v, v, lq); }
        }
    }
    const float2 s2 = bstats(ls, lq, 1.f / 2500.f, red, t);

    // ---- LN2 in place ----
    #pragma unroll
    for (int it = 0; it < 3; ++it) {
        const int idx = t + it * 1024;
        if (idx < 2500) {
            const int oh = idx / 50, ow = idx - oh * 50;
            const int p = oh * 52 + ow;
            y50[p] = (y50[p] - s2.x) * s2.y * g2[idx] + be2[idx];
        }
    }
    __syncthreads();

    // ---- L3: 50 -> conv3 -> relu -> y48 ----
    ls = 0.f; lq = 0.f;
    if (t < 576) {
        const int oh = t / 12, qc = t - oh * 12;
        const int ow0 = qc * 4;
        float acc[4];
        #pragma unroll
        for (int o = 0; o < 4; ++o) acc[o] = b3[oh * 48 + ow0 + o];
        #pragma unroll
        for (int kh = 0; kh < 3; ++kh) {
            const float* xp = y50 + (oh + kh) * 52 + ow0;
            float a[6];
            #pragma unroll
            for (int i = 0; i < 3; ++i) {
                const float2 v = *(const float2*)(xp + 2 * i);
                a[2 * i] = v.x; a[2 * i + 1] = v.y;
            }
            #pragma unroll
            for (int kw = 0; kw < 3; ++kw) {
                const float4 w4 = *(const float4*)(w3t + (size_t)(kh * 3 + kw) * 2304 + oh * 48 + ow0);
                acc[0] = fmaf(a[kw    ], w4.x, acc[0]);
                acc[1] = fmaf(a[kw + 1], w4.y, acc[1]);
                acc[2] = fmaf(a[kw + 2], w4.z, acc[2]);
                acc[3] = fmaf(a[kw + 3], w4.w, acc[3]);
            }
        }
        float4 st;
        #pragma unroll
        for (int o = 0; o < 4; ++o) {
            const float v = fmaxf(acc[o], 0.f);
            (&st.x)[o] = v; ls += v; lq = fmaf(v, v, lq);
        }
        *(float4*)(y48 + oh * 48 + ow0) = st;
    }
    const float2 s3 = bstats(ls, lq, 1.f / 2304.f, red, t);

    // ---- LN3 + pool -> xs24 ----
    if (t < 576) {
        const int ph = t / 24, pw = t - ph * 24;
        const int r0 = 2 * ph, c0 = 2 * pw;
        const float2 u0 = *(const float2*)(y48 + r0 * 48 + c0);
        const float2 u1 = *(const float2*)(y48 + (r0 + 1) * 48 + c0);
        const int i00 = r0 * 48 + c0, i10 = i00 + 48;
        const float v0 = (u0.x - s3.x) * s3.y * g3[i00]     + be3[i00];
        const float v1 = (u0.y - s3.x) * s3.y * g3[i00 + 1] + be3[i00 + 1];
        const float v2 = (u1.x - s3.x) * s3.y * g3[i10]     + be3[i10];
        const float v3 = (u1.y - s3.x) * s3.y * g3[i10 + 1] + be3[i10 + 1];
        xs24[ph * 24 + pw] = fmaxf(fmaxf(v0, v1), fmaxf(v2, v3));
    }
    __syncthreads();

    // ---- L4: 24 -> conv3 -> relu -> y22 ----
    ls = 0.f; lq = 0.f;
    if (t < 132) {
        const int oh = t / 6, qc = t - oh * 6;
        const int ow0 = qc * 4;
        float acc[4];
        #pragma unroll
        for (int o = 0; o < 4; ++o) acc[o] = (ow0 + o < 22) ? b4[oh * 22 + ow0 + o] : 0.f;
        #pragma unroll
        for (int kh = 0; kh < 3; ++kh) {
            const float* xp = xs24 + (oh + kh) * 24 + ow0;
            float a[6];
            #pragma unroll
            for (int i = 0; i < 3; ++i) {
                const float2 v = *(const float2*)(xp + 2 * i);
                a[2 * i] = v.x; a[2 * i + 1] = v.y;
            }
            #pragma unroll
            for (int kw = 0; kw < 3; ++kw) {
                const float4 w4 = *(const float4*)(w4t + ((size_t)(kh * 3 + kw) * 22 + oh) * 24 + ow0);
                acc[0] = fmaf(a[kw    ], w4.x, acc[0]);
                acc[1] = fmaf(a[kw + 1], w4.y, acc[1]);
                acc[2] = fmaf(a[kw + 2], w4.z, acc[2]);
                acc[3] = fmaf(a[kw + 3], w4.w, acc[3]);
            }
        }
        #pragma unroll
        for (int o = 0; o < 4; ++o) {
            const float v = fmaxf(acc[o], 0.f);
            y22[oh * 24 + ow0 + o] = v;
            if (ow0 + o < 22) { ls += v; lq = fmaf(v, v, lq); }
        }
    }
    const float2 s4 = bstats(ls, lq, 1.f / 484.f, red, t);

    // ---- LN4 in place ----
    if (t < 484) {
        const int oh = t / 22, ow = t - oh * 22;
        const int p = oh * 24 + ow;
        y22[p] = (y22[p] - s4.x) * s4.y * g4[t] + be4[t];
    }
    __syncthreads();

    // ---- L5: 22 -> conv3 -> relu -> y20 ----
    ls = 0.f; lq = 0.f;
    if (t < 100) {
        const int oh = t / 5, qc = t - oh * 5;
        const int ow0 = qc * 4;
        float acc[4];
        #pragma unroll
        for (int o = 0; o < 4; ++o) acc[o] = b5[oh * 20 + ow0 + o];
        #pragma unroll
        for (int kh = 0; kh < 3; ++kh) {
            const float* xp = y22 + (oh + kh) * 24 + ow0;
            float a[6];
            #pragma unroll
            for (int i = 0; i < 3; ++i) {
                const float2 v = *(const float2*)(xp + 2 * i);
                a[2 * i] = v.x; a[2 * i + 1] = v.y;
            }
            #pragma unroll
            for (int kw = 0; kw < 3; ++kw) {
                const float4 w4 = *(const float4*)(w5t + (size_t)(kh * 3 + kw) * 400 + oh * 20 + ow0);
                acc[0] = fmaf(a[kw    ], w4.x, acc[0]);
                acc[1] = fmaf(a[kw + 1], w4.y, acc[1]);
                acc[2] = fmaf(a[kw + 2], w4.z, acc[2]);
                acc[3] = fmaf(a[kw + 3], w4.w, acc[3]);
            }
        }
        #pragma unroll
        for (int o = 0; o < 4; ++o) {
            const float v = fmaxf(acc[o], 0.f);
            y20[oh * 20 + ow0 + o] = v;
            ls += v; lq = fmaf(v, v, lq);
        }
    }
    const float2 s5 = bstats(ls, lq, 1.f / 400.f, red, t);

    // ---- LN5 + pool -> xs10 ----
    if (t < 100) {
        const int ph = t / 10, pw = t - ph * 10;
        const int r0 = 2 * ph, c0 = 2 * pw;
        const float2 u0 = *(const float2*)(y20 + r0 * 20 + c0);
        const float2 u1 = *(const float2*)(y20 + (r0 + 1) * 20 + c0);
        const int i00 = r0 * 20 + c0, i10 = i00 + 20;
        const float v0 = (u0.x - s5.x) * s5.y * g5[i00]     + be5[i00];
        const float v1 = (u0.y - s5.x) * s5.y * g5[i00 + 1] + be5[i00 + 1];
        const float v2 = (u1.x - s5.x) * s5.y * g5[i10]     + be5[i10];
        const float v3 = (u1.y - s5.x) * s5.y * g5[i10 + 1] + be5[i10 + 1];
        xs10[ph * 10 + pw] = fmaxf(fmaxf(v0, v1), fmaxf(v2, v3));
    }
    __syncthreads();

    // ---- L6: 10 -> conv3 -> relu -> y8 ----
    ls = 0.f; lq = 0.f;
    if (t < 16) {
        const int oh = t / 2, qc = t - oh * 2;
        const int ow0 = qc * 4;
        float acc[4];
        #pragma unroll
        for (int o = 0; o < 4; ++o) acc[o] = b6[oh * 8 + ow0 + o];
        #pragma unroll
        for (int kh = 0; kh < 3; ++kh) {
            const float* xp = xs10 + (oh + kh) * 10 + ow0;
            float a[6];
            #pragma unroll
            for (int i = 0; i < 3; ++i) {
                const float2 v = *(const float2*)(xp + 2 * i);
                a[2 * i] = v.x; a[2 * i + 1] = v.y;
            }
            #pragma unroll
            for (int kw = 0; kw < 3; ++kw) {
                const float4 w4 = *(const float4*)(w6t + (size_t)(kh * 3 + kw) * 64 + oh * 8 + ow0);
                acc[0] = fmaf(a[kw    ], w4.x, acc[0]);
                acc[1] = fmaf(a[kw + 1], w4.y, acc[1]);
                acc[2] = fmaf(a[kw + 2], w4.z, acc[2]);
                acc[3] = fmaf(a[kw + 3], w4.w, acc[3]);
            }
        }
        #pragma unroll
        for (int o = 0; o < 4; ++o) {
            const float v = fmaxf(acc[o], 0.f);
            y8[oh * 8 + ow0 + o] = v;
            ls += v; lq = fmaf(v, v, lq);
        }
    }
    const float2 s6 = bstats(ls, lq, 1.f / 64.f, red, t);

    // ---- LN6 -> h ----
    if (t < 64) h[t] = (y8[t] - s6.x) * s6.y * g6[t] + be6[t];
    __syncthreads();

    // ---- FC 64 -> 1000 (1 task/thread) + softmax ----
    float lj = -INFINITY;
    if (t < 1000) {
        const float4* wr = (const float4*)(fcw + (size_t)t * 64);
        float acc = fcb[t];
        #pragma unroll
        for (int k = 0; k < 16; ++k) {
            const float4 w4 = wr[k];
            acc = fmaf(h[4 * k], w4.x,
                  fmaf(h[4 * k + 1], w4.y,
                  fmaf(h[4 * k + 2], w4.z,
                  fmaf(h[4 * k + 3], w4.w, acc))));
        }
        lj = acc;
    }
    float mx = lj;
    #pragma unroll
    for (int off = 32; off > 0; off >>= 1) mx = fmaxf(mx, __shfl_down(mx, off, 64));
    if (lane == 0) red[t >> 6][0] = mx;
    __syncthreads();
    float gmax = red[0][0];
    #pragma unroll
    for (int w = 1; w < 16; ++w) gmax = fmaxf(gmax, red[w][0]);

    const float e = (t < 1000) ? __expf(lj - gmax) : 0.f;
    float ssum = e;
    #pragma unroll
    for (int off = 32; off > 0; off >>= 1) ssum += __shfl_down(ssum, off, 64);
    if (lane == 0) red[t >> 6][1] = ssum;
    __syncthreads();
    float tot = 0.f;
    #pragma unroll
    for (int w = 0; w < 16; ++w) tot += red[w][1];
    if (t < 1000) out[(size_t)b * 1000 + t] = e / tot;
}

extern "C" void kernel_launch(void* const* d_in, const int* in_sizes, int n_in,
                              void* d_out, int out_size, void* d_ws, size_t ws_size,
                              hipStream_t stream) {
    const float* x   = (const float*)d_in[0];
    const float* w1  = (const float*)d_in[1];
    const float* b1  = (const float*)d_in[2];
    const float* g1  = (const float*)d_in[3];
    const float* be1 = (const float*)d_in[4];
    const float* w2  = (const float*)d_in[5];
    const float* b2  = (const float*)d_in[6];
    const float* g2  = (const float*)d_in[7];
    const float* be2 = (const float*)d_in[8];
    const float* w3  = (const float*)d_in[9];
    const float* b3  = (const float*)d_in[10];
    const float* g3  = (const float*)d_in[11];
    const float* be3 = (const float*)d_in[12];
    const float* w4  = (const float*)d_in[13];
    const float* b4  = (const float*)d_in[14];
    const float* g4  = (const float*)d_in[15];
    const float* be4 = (const float*)d_in[16];
    const float* w5  = (const float*)d_in[17];
    const float* b5  = (const float*)d_in[18];
    const float* g5  = (const float*)d_in[19];
    const float* be5 = (const float*)d_in[20];
    const float* w6  = (const float*)d_in[21];
    const float* b6  = (const float*)d_in[22];
    const float* g6  = (const float*)d_in[23];
    const float* be6 = (const float*)d_in[24];
    const float* fcw = (const float*)d_in[25];
    const float* fcb = (const float*)d_in[26];

    float* y1p  = (float*)d_ws;                 // 128*109*112 = 1,562,624
    float* w1t  = y1p  + 1562624;               // 49*109*112  =   598,192
    float* w2t  = w1t  + 598192;                // 25*50*52    =    65,000
    float* w3t  = w2t  + 65000;                 // 9*2304      =    20,736
    float* w4t  = w3t  + 20736;                 // 9*22*24     =     4,752
    float* w5t  = w4t  + 4752;                  // 9*400       =     3,600
    float* w6t  = w5t  + 3600;                  // 9*64        =       576
    float* part = w6t  + 576;                   // 128*14*2    =     3,584
    float* g1pp = part + 3584;                  // 2916*4      =    11,664
    float* be1pp= g1pp + 11664;                 // 2916*4      =    11,664

    transpose_w1<<<186, 256, 0, stream>>>(w1, w1t);

    conv1<<<dim3(14, 65), 448, 0, stream>>>(x, w1t, b1, y1p, part,
                                            w2, w3, w4, w5, w6, g1, be1,
                                            w2t, w3t, w4t, w5t, w6t,
                                            (float4*)g1pp, (float4*)be1pp);

    tail<<<128, 1024, 0, stream>>>(y1p, part,
                                   (const float4*)g1pp, (const float4*)be1pp,
                                   w2t, b2, g2, be2,
                                   w3t, b3, g3, be3,
                                   w4t, b4, g4, be4,
                                   w5t, b5, g5, be5,
                                   w6t, b6, g6, be6,
                                   fcw, fcb, (float*)d_out);
}

// Round 8
// 64.653 us; speedup vs baseline: 1.3327x; 1.0477x over previous
//
#include <hip/hip_runtime.h>
#include <math.h>

static constexpr float kEps = 1e-5f;

// ---------- kernel 1: transpose x -> xt[pos][128 samples] (+ side packs) ----------
// 784 tiles of 64 pos x 128 smp via LDS (pad 133 -> conflict-free both phases).
// Blocks 784..797 do the small weight transposes + LN1 pool-param packing.
__global__ __launch_bounds__(256)
void xpose(const float* __restrict__ x, float* __restrict__ xt,
           const float* __restrict__ w2, const float* __restrict__ w3,
           const float* __restrict__ w4, const float* __restrict__ w5,
           const float* __restrict__ w6,
           const float* __restrict__ g1, const float* __restrict__ be1,
           float* __restrict__ w2t, float* __restrict__ w3t,
           float* __restrict__ w4t, float* __restrict__ w5t,
           float* __restrict__ w6t,
           float4* __restrict__ g1p, float4* __restrict__ be1p)
{
    const int bid = blockIdx.x, t = threadIdx.x;
    if (bid >= 784) {
        const int tid = (bid - 784) * 256 + t;
        const int nt  = 14 * 256;
        for (int i = tid; i < 25 * 50 * 52; i += nt) {          // w2t [25][50][52]
            const int kk = i / (50 * 52), r = i % (50 * 52);
            const int oh = r / 52, ow = r % 52;
            w2t[i] = (ow < 50) ? w2[(oh * 50 + ow) * 25 + kk] : 0.f;
        }
        for (int i = tid; i < 9 * 2304; i += nt) {              // w3t [9][2304]
            const int kk = i / 2304, idx = i % 2304;
            w3t[i] = w3[idx * 9 + kk];
        }
        for (int i = tid; i < 9 * 22 * 24; i += nt) {           // w4t [9][22][24]
            const int kk = i / (22 * 24), r = i % (22 * 24);
            const int oh = r / 24, ow = r % 24;
            w4t[i] = (ow < 22) ? w4[(oh * 22 + ow) * 9 + kk] : 0.f;
        }
        for (int i = tid; i < 9 * 400; i += nt) {               // w5t [9][400]
            const int kk = i / 400, idx = i % 400;
            w5t[i] = w5[idx * 9 + kk];
        }
        for (int i = tid; i < 9 * 64; i += nt) {                // w6t [9][64]
            const int kk = i / 64, idx = i % 64;
            w6t[i] = w6[idx * 9 + kk];
        }
        for (int i = tid; i < 54 * 54; i += nt) {               // pool-window params
            const int ph = i / 54, pw = i - ph * 54;
            const int i00 = (2 * ph) * 109 + 2 * pw, i10 = i00 + 109;
            g1p[i]  = make_float4(g1[i00],  g1[i00 + 1],  g1[i10],  g1[i10 + 1]);
            be1p[i] = make_float4(be1[i00], be1[i00 + 1], be1[i10], be1[i10 + 1]);
        }
        return;
    }

    __shared__ float ls[64 * 133];
    const int pos0 = bid * 64;
    // phase A: coalesced read x[s][pos0+j], LDS write bank-step 5 (2-way, free)
    for (int i = t; i < 8192; i += 256) {
        const int s = i >> 6, j = i & 63;
        ls[j * 133 + s] = x[(size_t)s * 50176 + pos0 + j];
    }
    __syncthreads();
    // phase B: LDS read bank-step 1, coalesced write xt[pos0+j][s]
    for (int i = t; i < 8192; i += 256) {
        const int j = i >> 7, s = i & 127;
        xt[(size_t)(pos0 + j) * 128 + s] = ls[j * 133 + s];
    }
}

// ---------- kernel 2: conv1, sample-in-lane ----------
// Block (oh, grp): 8 waves; lane = sample (grp*64+lane). Wave handles chunks of
// 4 output cols via a 7x13 register x-tile (reused across the 4 outputs).
// Weights w1[idx][kk] are wave-uniform -> SGPR loads (no transpose needed).
__global__ __launch_bounds__(512)
void conv1(const float* __restrict__ xt, const float* __restrict__ w1,
           const float* __restrict__ bias, float* __restrict__ y,
           float* __restrict__ partial)
{
    __shared__ float redS[8][64], redQ[8][64];
    const int oh = blockIdx.x;        // 0..108
    const int grp = blockIdx.y;       // 0..1
    const int t = threadIdx.x;
    const int w = t >> 6, lane = t & 63;
    const int smp = grp * 64 + lane;

    float lsum = 0.f, lsq = 0.f;
    for (int ch = w; ch < 28; ch += 8) {
        const int ow0 = ch * 4;
        // x register tile: rows 2oh..2oh+6, cols 2ow0..2ow0+12 (col idx may run
        // past 223 into next row for the tail chunk -- in-bounds, discarded)
        float xv[7][13];
        const size_t base = ((size_t)(2 * oh) * 224 + 2 * ow0) * 128 + smp;
        #pragma unroll
        for (int r = 0; r < 7; ++r) {
            #pragma unroll
            for (int c = 0; c < 13; ++c)
                xv[r][c] = xt[base + ((size_t)(r * 224 + c)) * 128];
        }
        #pragma unroll
        for (int o = 0; o < 4; ++o) {
            const int ow = ow0 + o;
            if (ow < 109) {
                const int idx = __builtin_amdgcn_readfirstlane(oh * 109 + ow);
                const float* __restrict__ wr = w1 + (size_t)idx * 49;
                float acc = bias[idx];
                #pragma unroll
                for (int kh = 0; kh < 7; ++kh) {
                    #pragma unroll
                    for (int kw = 0; kw < 7; ++kw)
                        acc = fmaf(xv[kh][2 * o + kw], wr[kh * 7 + kw], acc);
                }
                const float v = fmaxf(acc, 0.f);
                y[((size_t)smp * 109 + oh) * 112 + ow] = v;
                lsum += v; lsq = fmaf(v, v, lsq);
            }
        }
    }
    redS[w][lane] = lsum; redQ[w][lane] = lsq;
    __syncthreads();
    if (w == 0) {
        float s = 0.f, q = 0.f;
        #pragma unroll
        for (int i = 0; i < 8; ++i) { s += redS[i][lane]; q += redQ[i][lane]; }
        *(float2*)(partial + ((size_t)smp * 109 + oh) * 2) = make_float2(s, q);
    }
}

// ---------- block stats for 16 waves: one barrier, all threads get result ----------
__device__ inline float2 bstats(float ls, float lq, float invN, float (*red)[2], int t)
{
    #pragma unroll
    for (int off = 32; off > 0; off >>= 1) {
        ls += __shfl_down(ls, off, 64);
        lq += __shfl_down(lq, off, 64);
    }
    if ((t & 63) == 0) { red[t >> 6][0] = ls; red[t >> 6][1] = lq; }
    __syncthreads();
    float s = 0.f, q = 0.f;
    #pragma unroll
    for (int w = 0; w < 16; ++w) { s += red[w][0]; q += red[w][1]; }
    const float m = s * invN;
    return make_float2(m, rsqrtf(q * invN - m * m + kEps));
}

// ---------- kernel 3: everything after conv1, one 1024-thread block per sample ----------
__global__ __launch_bounds__(1024)
void tail(const float* __restrict__ y1, const float* __restrict__ partial,
          const float4* __restrict__ g1p, const float4* __restrict__ be1p,
          const float* __restrict__ w2t, const float* __restrict__ b2,
          const float* __restrict__ g2, const float* __restrict__ be2,
          const float* __restrict__ w3t, const float* __restrict__ b3,
          const float* __restrict__ g3, const float* __restrict__ be3,
          const float* __restrict__ w4t, const float* __restrict__ b4,
          const float* __restrict__ g4, const float* __restrict__ be4,
          const float* __restrict__ w5t, const float* __restrict__ b5,
          const float* __restrict__ g5, const float* __restrict__ be5,
          const float* __restrict__ w6t, const float* __restrict__ b6,
          const float* __restrict__ g6, const float* __restrict__ be6,
          const float* __restrict__ fcw, const float* __restrict__ fcb,
          float* __restrict__ out)
{
    __shared__ __align__(16) float xs54[54 * 54 + 8];
    __shared__ __align__(16) float y50[50 * 52];
    __shared__ __align__(16) float y48[48 * 48];
    __shared__ __align__(16) float xs24[24 * 24 + 8];
    __shared__ __align__(16) float y22[22 * 24];
    __shared__ __align__(16) float y20[20 * 20];
    __shared__ __align__(16) float xs10[100];
    __shared__ float y8[64], h[64];
    __shared__ float red[16][2];

    const int b = blockIdx.x, t = threadIdx.x;
    const int lane = t & 63;

    // ---- LN1 stats from 109 per-row partials: per-wave, barrier-free ----
    float s, q;
    {
        const float2 p = *(const float2*)(partial + ((size_t)b * 109 + lane) * 2);
        s = p.x; q = p.y;
        if (lane < 45) {
            const float2 p2 = *(const float2*)(partial + ((size_t)b * 109 + 64 + lane) * 2);
            s += p2.x; q += p2.y;
        }
    }
    #pragma unroll
    for (int off = 32; off > 0; off >>= 1) {
        s += __shfl_down(s, off, 64);
        q += __shfl_down(q, off, 64);
    }
    s = __shfl(s, 0, 64); q = __shfl(q, 0, 64);
    const float m1 = s / 11881.f;
    const float r1 = rsqrtf(q / 11881.f - m1 * m1 + kEps);

    // ---- LN1 + 2x2 pool -> xs54 ----
    const float* yb = y1 + (size_t)b * 109 * 112;
    #pragma unroll
    for (int it = 0; it < 3; ++it) {
        const int idx = t + it * 1024;
        if (idx < 54 * 54) {
            const int ph = idx / 54, pw = idx - ph * 54;
            const int r0 = 2 * ph, c0 = 2 * pw;
            const float2 u0 = *(const float2*)(yb + r0 * 112 + c0);
            const float2 u1 = *(const float2*)(yb + (r0 + 1) * 112 + c0);
            const float4 g = g1p[idx], be = be1p[idx];
            const float v0 = (u0.x - m1) * r1 * g.x + be.x;
            const float v1 = (u0.y - m1) * r1 * g.y + be.y;
            const float v2 = (u1.x - m1) * r1 * g.z + be.z;
            const float v3 = (u1.y - m1) * r1 * g.w + be.w;
            xs54[ph * 54 + pw] = fmaxf(fmaxf(v0, v1), fmaxf(v2, v3));
        }
    }
    __syncthreads();

    // ---- L2: 54 -> conv5 -> relu -> y50 ----
    float ls = 0.f, lq = 0.f;
    if (t < 650) {
        const int oh = t / 13, qc = t - oh * 13;
        const int ow0 = qc * 4;
        float acc[4];
        #pragma unroll
        for (int o = 0; o < 4; ++o) acc[o] = (ow0 + o < 50) ? b2[oh * 50 + ow0 + o] : 0.f;
        #pragma unroll
        for (int kh = 0; kh < 5; ++kh) {
            const float* xp = xs54 + (oh + kh) * 54 + ow0;
            float a[8];
            #pragma unroll
            for (int i = 0; i < 4; ++i) {
                const float2 v = *(const float2*)(xp + 2 * i);
                a[2 * i] = v.x; a[2 * i + 1] = v.y;
            }
            #pragma unroll
            for (int kw = 0; kw < 5; ++kw) {
                const float4 w4 = *(const float4*)(w2t + ((size_t)(kh * 5 + kw) * 50 + oh) * 52 + ow0);
                acc[0] = fmaf(a[kw    ], w4.x, acc[0]);
                acc[1] = fmaf(a[kw + 1], w4.y, acc[1]);
                acc[2] = fmaf(a[kw + 2], w4.z, acc[2]);
                acc[3] = fmaf(a[kw + 3], w4.w, acc[3]);
            }
        }
        #pragma unroll
        for (int o = 0; o < 4; ++o) {
            const float v = fmaxf(acc[o], 0.f);
            y50[oh * 52 + ow0 + o] = v;
            if (ow0 + o < 50) { ls += v; lq = fmaf(v, v, lq); }
        }
    }
    const float2 s2 = bstats(ls, lq, 1.f / 2500.f, red, t);

    // ---- LN2 in place ----
    #pragma unroll
    for (int it = 0; it < 3; ++it) {
        const int idx = t + it * 1024;
        if (idx < 2500) {
            const int oh = idx / 50, ow = idx - oh * 50;
            const int p = oh * 52 + ow;
            y50[p] = (y50[p] - s2.x) * s2.y * g2[idx] + be2[idx];
        }
    }
    __syncthreads();

    // ---- L3: 50 -> conv3 -> relu -> y48 ----
    ls = 0.f; lq = 0.f;
    if (t < 576) {
        const int oh = t / 12, qc = t - oh * 12;
        const int ow0 = qc * 4;
        float acc[4];
        #pragma unroll
        for (int o = 0; o < 4; ++o) acc[o] = b3[oh * 48 + ow0 + o];
        #pragma unroll
        for (int kh = 0; kh < 3; ++kh) {
            const float* xp = y50 + (oh + kh) * 52 + ow0;
            float a[6];
            #pragma unroll
            for (int i = 0; i < 3; ++i) {
                const float2 v = *(const float2*)(xp + 2 * i);
                a[2 * i] = v.x; a[2 * i + 1] = v.y;
            }
            #pragma unroll
            for (int kw = 0; kw < 3; ++kw) {
                const float4 w4 = *(const float4*)(w3t + (size_t)(kh * 3 + kw) * 2304 + oh * 48 + ow0);
                acc[0] = fmaf(a[kw    ], w4.x, acc[0]);
                acc[1] = fmaf(a[kw + 1], w4.y, acc[1]);
                acc[2] = fmaf(a[kw + 2], w4.z, acc[2]);
                acc[3] = fmaf(a[kw + 3], w4.w, acc[3]);
            }
        }
        float4 st;
        #pragma unroll
        for (int o = 0; o < 4; ++o) {
            const float v = fmaxf(acc[o], 0.f);
            (&st.x)[o] = v; ls += v; lq = fmaf(v, v, lq);
        }
        *(float4*)(y48 + oh * 48 + ow0) = st;
    }
    const float2 s3 = bstats(ls, lq, 1.f / 2304.f, red, t);

    // ---- LN3 + pool -> xs24 ----
    if (t < 576) {
        const int ph = t / 24, pw = t - ph * 24;
        const int r0 = 2 * ph, c0 = 2 * pw;
        const float2 u0 = *(const float2*)(y48 + r0 * 48 + c0);
        const float2 u1 = *(const float2*)(y48 + (r0 + 1) * 48 + c0);
        const int i00 = r0 * 48 + c0, i10 = i00 + 48;
        const float v0 = (u0.x - s3.x) * s3.y * g3[i00]     + be3[i00];
        const float v1 = (u0.y - s3.x) * s3.y * g3[i00 + 1] + be3[i00 + 1];
        const float v2 = (u1.x - s3.x) * s3.y * g3[i10]     + be3[i10];
        const float v3 = (u1.y - s3.x) * s3.y * g3[i10 + 1] + be3[i10 + 1];
        xs24[ph * 24 + pw] = fmaxf(fmaxf(v0, v1), fmaxf(v2, v3));
    }
    __syncthreads();

    // ---- L4: 24 -> conv3 -> relu -> y22 ----
    ls = 0.f; lq = 0.f;
    if (t < 132) {
        const int oh = t / 6, qc = t - oh * 6;
        const int ow0 = qc * 4;
        float acc[4];
        #pragma unroll
        for (int o = 0; o < 4; ++o) acc[o] = (ow0 + o < 22) ? b4[oh * 22 + ow0 + o] : 0.f;
        #pragma unroll
        for (int kh = 0; kh < 3; ++kh) {
            const float* xp = xs24 + (oh + kh) * 24 + ow0;
            float a[6];
            #pragma unroll
            for (int i = 0; i < 3; ++i) {
                const float2 v = *(const float2*)(xp + 2 * i);
                a[2 * i] = v.x; a[2 * i + 1] = v.y;
            }
            #pragma unroll
            for (int kw = 0; kw < 3; ++kw) {
                const float4 w4 = *(const float4*)(w4t + ((size_t)(kh * 3 + kw) * 22 + oh) * 24 + ow0);
                acc[0] = fmaf(a[kw    ], w4.x, acc[0]);
                acc[1] = fmaf(a[kw + 1], w4.y, acc[1]);
                acc[2] = fmaf(a[kw + 2], w4.z, acc[2]);
                acc[3] = fmaf(a[kw + 3], w4.w, acc[3]);
            }
        }
        #pragma unroll
        for (int o = 0; o < 4; ++o) {
            const float v = fmaxf(acc[o], 0.f);
            y22[oh * 24 + ow0 + o] = v;
            if (ow0 + o < 22) { ls += v; lq = fmaf(v, v, lq); }
        }
    }
    const float2 s4 = bstats(ls, lq, 1.f / 484.f, red, t);

    // ---- LN4 in place ----
    if (t < 484) {
        const int oh = t / 22, ow = t - oh * 22;
        const int p = oh * 24 + ow;
        y22[p] = (y22[p] - s4.x) * s4.y * g4[t] + be4[t];
    }
    __syncthreads();

    // ---- L5: 22 -> conv3 -> relu -> y20 ----
    ls = 0.f; lq = 0.f;
    if (t < 100) {
        const int oh = t / 5, qc = t - oh * 5;
        const int ow0 = qc * 4;
        float acc[4];
        #pragma unroll
        for (int o = 0; o < 4; ++o) acc[o] = b5[oh * 20 + ow0 + o];
        #pragma unroll
        for (int kh = 0; kh < 3; ++kh) {
            const float* xp = y22 + (oh + kh) * 24 + ow0;
            float a[6];
            #pragma unroll
            for (int i = 0; i < 3; ++i) {
                const float2 v = *(const float2*)(xp + 2 * i);
                a[2 * i] = v.x; a[2 * i + 1] = v.y;
            }
            #pragma unroll
            for (int kw = 0; kw < 3; ++kw) {
                const float4 w4 = *(const float4*)(w5t + (size_t)(kh * 3 + kw) * 400 + oh * 20 + ow0);
                acc[0] = fmaf(a[kw    ], w4.x, acc[0]);
                acc[1] = fmaf(a[kw + 1], w4.y, acc[1]);
                acc[2] = fmaf(a[kw + 2], w4.z, acc[2]);
                acc[3] = fmaf(a[kw + 3], w4.w, acc[3]);
            }
        }
        #pragma unroll
        for (int o = 0; o < 4; ++o) {
            const float v = fmaxf(acc[o], 0.f);
            y20[oh * 20 + ow0 + o] = v;
            ls += v; lq = fmaf(v, v, lq);
        }
    }
    const float2 s5 = bstats(ls, lq, 1.f / 400.f, red, t);

    // ---- LN5 + pool -> xs10 ----
    if (t < 100) {
        const int ph = t / 10, pw = t - ph * 10;
        const int r0 = 2 * ph, c0 = 2 * pw;
        const float2 u0 = *(const float2*)(y20 + r0 * 20 + c0);
        const float2 u1 = *(const float2*)(y20 + (r0 + 1) * 20 + c0);
        const int i00 = r0 * 20 + c0, i10 = i00 + 20;
        const float v0 = (u0.x - s5.x) * s5.y * g5[i00]     + be5[i00];
        const float v1 = (u0.y - s5.x) * s5.y * g5[i00 + 1] + be5[i00 + 1];
        const float v2 = (u1.x - s5.x) * s5.y * g5[i10]     + be5[i10];
        const float v3 = (u1.y - s5.x) * s5.y * g5[i10 + 1] + be5[i10 + 1];
        xs10[ph * 10 + pw] = fmaxf(fmaxf(v0, v1), fmaxf(v2, v3));
    }
    __syncthreads();

    // ---- L6: 10 -> conv3 -> relu -> y8 ----
    ls = 0.f; lq = 0.f;
    if (t < 16) {
        const int oh = t / 2, qc = t - oh * 2;
        const int ow0 = qc * 4;
        float acc[4];
        #pragma unroll
        for (int o = 0; o < 4; ++o) acc[o] = b6[oh * 8 + ow0 + o];
        #pragma unroll
        for (int kh = 0; kh < 3; ++kh) {
            const float* xp = xs10 + (oh + kh) * 10 + ow0;
            float a[6];
            #pragma unroll
            for (int i = 0; i < 3; ++i) {
                const float2 v = *(const float2*)(xp + 2 * i);
                a[2 * i] = v.x; a[2 * i + 1] = v.y;
            }
            #pragma unroll
            for (int kw = 0; kw < 3; ++kw) {
                const float4 w4 = *(const float4*)(w6t + (size_t)(kh * 3 + kw) * 64 + oh * 8 + ow0);
                acc[0] = fmaf(a[kw    ], w4.x, acc[0]);
                acc[1] = fmaf(a[kw + 1], w4.y, acc[1]);
                acc[2] = fmaf(a[kw + 2], w4.z, acc[2]);
                acc[3] = fmaf(a[kw + 3], w4.w, acc[3]);
            }
        }
        #pragma unroll
        for (int o = 0; o < 4; ++o) {
            const float v = fmaxf(acc[o], 0.f);
            y8[oh * 8 + ow0 + o] = v;
            ls += v; lq = fmaf(v, v, lq);
        }
    }
    const float2 s6 = bstats(ls, lq, 1.f / 64.f, red, t);

    // ---- LN6 -> h ----
    if (t < 64) h[t] = (y8[t] - s6.x) * s6.y * g6[t] + be6[t];
    __syncthreads();

    // ---- FC 64 -> 1000 (1 task/thread) + softmax ----
    float lj = -INFINITY;
    if (t < 1000) {
        const float4* wr = (const float4*)(fcw + (size_t)t * 64);
        float acc = fcb[t];
        #pragma unroll
        for (int k = 0; k < 16; ++k) {
            const float4 w4 = wr[k];
            acc = fmaf(h[4 * k], w4.x,
                  fmaf(h[4 * k + 1], w4.y,
                  fmaf(h[4 * k + 2], w4.z,
                  fmaf(h[4 * k + 3], w4.w, acc))));
        }
        lj = acc;
    }
    float mx = lj;
    #pragma unroll
    for (int off = 32; off > 0; off >>= 1) mx = fmaxf(mx, __shfl_down(mx, off, 64));
    if (lane == 0) red[t >> 6][0] = mx;
    __syncthreads();
    float gmax = red[0][0];
    #pragma unroll
    for (int w = 1; w < 16; ++w) gmax = fmaxf(gmax, red[w][0]);

    const float e = (t < 1000) ? __expf(lj - gmax) : 0.f;
    float ssum = e;
    #pragma unroll
    for (int off = 32; off > 0; off >>= 1) ssum += __shfl_down(ssum, off, 64);
    if (lane == 0) red[t >> 6][1] = ssum;
    __syncthreads();
    float tot = 0.f;
    #pragma unroll
    for (int w = 0; w < 16; ++w) tot += red[w][1];
    if (t < 1000) out[(size_t)b * 1000 + t] = e / tot;
}

extern "C" void kernel_launch(void* const* d_in, const int* in_sizes, int n_in,
                              void* d_out, int out_size, void* d_ws, size_t ws_size,
                              hipStream_t stream) {
    const float* x   = (const float*)d_in[0];
    const float* w1  = (const float*)d_in[1];
    const float* b1  = (const float*)d_in[2];
    const float* g1  = (const float*)d_in[3];
    const float* be1 = (const float*)d_in[4];
    const float* w2  = (const float*)d_in[5];
    const float* b2  = (const float*)d_in[6];
    const float* g2  = (const float*)d_in[7];
    const float* be2 = (const float*)d_in[8];
    const float* w3  = (const float*)d_in[9];
    const float* b3  = (const float*)d_in[10];
    const float* g3  = (const float*)d_in[11];
    const float* be3 = (const float*)d_in[12];
    const float* w4  = (const float*)d_in[13];
    const float* b4  = (const float*)d_in[14];
    const float* g4  = (const float*)d_in[15];
    const float* be4 = (const float*)d_in[16];
    const float* w5  = (const float*)d_in[17];
    const float* b5  = (const float*)d_in[18];
    const float* g5  = (const float*)d_in[19];
    const float* be5 = (const float*)d_in[20];
    const float* w6  = (const float*)d_in[21];
    const float* b6  = (const float*)d_in[22];
    const float* g6  = (const float*)d_in[23];
    const float* be6 = (const float*)d_in[24];
    const float* fcw = (const float*)d_in[25];
    const float* fcb = (const float*)d_in[26];

    float* xt   = (float*)d_ws;                 // 50176*128  = 6,422,528
    float* y1p  = xt   + 6422528;               // 128*109*112= 1,562,624
    float* w2t  = y1p  + 1562624;               // 25*50*52   =    65,000
    float* w3t  = w2t  + 65000;                 // 9*2304     =    20,736
    float* w4t  = w3t  + 20736;                 // 9*22*24    =     4,752
    float* w5t  = w4t  + 4752;                  // 9*400      =     3,600
    float* w6t  = w5t  + 3600;                  // 9*64       =       576
    float* part = w6t  + 576;                   // 128*109*2  =    27,904
    float* g1pp = part + 27904;                 // 2916*4     =    11,664
    float* be1pp= g1pp + 11664;                 // 2916*4     =    11,664

    xpose<<<798, 256, 0, stream>>>(x, xt,
                                   w2, w3, w4, w5, w6, g1, be1,
                                   w2t, w3t, w4t, w5t, w6t,
                                   (float4*)g1pp, (float4*)be1pp);

    conv1<<<dim3(109, 2), 512, 0, stream>>>(xt, w1, b1, y1p, part);

    tail<<<128, 1024, 0, stream>>>(y1p, part,
                                   (const float4*)g1pp, (const float4*)be1pp,
                                   w2t, b2, g2, be2,
                                   w3t, b3, g3, be3,
                                   w4t, b4, g4, be4,
                                   w5t, b5, g5, be5,
                                   w6t, b6, g6, be6,
                                   fcw, fcb, (float*)d_out);
}